// Round 1
// baseline (383.856 us; speedup 1.0000x reference)
//
#include <hip/hip_runtime.h>
#include <math.h>

// Problem constants (from reference setup_inputs): B=512, S=4096, H=32, D=16
#define BB     512
#define SS     4096
#define HH     32
#define DD     16
#define CHUNK  256                 // encoder rows staged per LDS chunk
#define NCH    (SS / CHUNK)        // 16 chunks per block
#define STRIDE 33                  // +1 float pad: bank = (t+h)%32 -> conflict-free
#define NT     256                 // threads per block (4 waves)
#define EPSI   1e-8f

__global__ __launch_bounds__(NT, 2)
void attn_cos_logsoftmax(const float* __restrict__ dec,   // [B,H]
                         const float* __restrict__ enc,   // [B,S,H]
                         const float* __restrict__ Wq,    // [D,H]
                         const float* __restrict__ bq,    // [D]
                         const float* __restrict__ Wk,    // [D,H]
                         const float* __restrict__ bk,    // [D]
                         float* __restrict__ out)         // [B,1,S]
{
    __shared__ float wqT[HH * DD];          // wqT[h*16+d] -- wave-uniform broadcast reads
    __shared__ float buf[CHUNK * STRIDE];   // padded encoder chunk
    __shared__ float red[8];                // cross-wave reduction scratch

    const int t = threadIdx.x;
    const int b = blockIdx.x;

    // Stage Wq transposed into LDS (512 elems, 2 per thread)
    for (int e = t; e < DD * HH; e += NT) {
        int d = e >> 5;      // e / 32
        int h = e & 31;      // e % 32
        wqT[h * DD + d] = Wq[e];
    }

    // bq into registers (uniform -> scalar loads)
    float bqr[DD];
#pragma unroll
    for (int d = 0; d < DD; ++d) bqr[d] = bq[d];

    // kn = normalize(dec[b] @ Wk^T + bk): block-uniform, compute redundantly per thread
    float kn[DD];
    {
        float dh[HH];
#pragma unroll
        for (int h = 0; h < HH; ++h) dh[h] = dec[b * HH + h];
        float ss = 0.f;
#pragma unroll
        for (int d = 0; d < DD; ++d) {
            float a = bk[d];
#pragma unroll
            for (int h = 0; h < HH; ++h) a = fmaf(Wk[d * HH + h], dh[h], a);
            kn[d] = a;
            ss = fmaf(a, a, ss);
        }
        float inv = 1.f / fmaxf(sqrtf(ss), EPSI);
#pragma unroll
        for (int d = 0; d < DD; ++d) kn[d] *= inv;
    }

    const float4* encb = (const float4*)(enc + (size_t)b * SS * HH);

    // Prologue: prefetch chunk 0 into registers (8 float4 / thread = 32 KiB / block)
    float4 pf[8];
#pragma unroll
    for (int i = 0; i < 8; ++i) pf[i] = encb[i * NT + t];

    __syncthreads();  // wqT visible

    float att[NCH];

    for (int c = 0; c < NCH; ++c) {
        // Drain prefetch registers into padded LDS
#pragma unroll
        for (int i = 0; i < 8; ++i) {
            int idx = i * NT + t;        // float4 index within chunk
            int row = idx >> 3;          // 8 float4 per row
            int c4  = idx & 7;
            float* p = &buf[row * STRIDE + c4 * 4];
            p[0] = pf[i].x; p[1] = pf[i].y; p[2] = pf[i].z; p[3] = pf[i].w;
        }
        __syncthreads();

        // Issue next chunk's global loads now; s_waitcnt lands at next iter's
        // ds_write, so the whole compute phase hides HBM latency.
        if (c + 1 < NCH) {
            const float4* src = encb + (size_t)(c + 1) * (CHUNK * HH / 4);
#pragma unroll
            for (int i = 0; i < 8; ++i) pf[i] = src[i * NT + t];
        }

        // Compute q for my row, then cosine vs kn
        float q[DD];
#pragma unroll
        for (int d = 0; d < DD; ++d) q[d] = bqr[d];
        const float* hrow = &buf[t * STRIDE];
#pragma unroll
        for (int h = 0; h < HH; ++h) {
            float hv = hrow[h];                 // ds_read_b32, conflict-free
            const float* w = &wqT[h * DD];      // uniform -> broadcast b128
#pragma unroll
            for (int d = 0; d < DD; ++d) q[d] = fmaf(w[d], hv, q[d]);
        }
        float ss = 0.f, num = 0.f;
#pragma unroll
        for (int d = 0; d < DD; ++d) {
            ss  = fmaf(q[d], q[d], ss);
            num = fmaf(q[d], kn[d], num);
        }
        att[c] = num / fmaxf(sqrtf(ss), EPSI);

        __syncthreads();  // all rows consumed before buf is overwritten
    }

    // --- block log-softmax over the 4096 attention values ---
    float m = -INFINITY;
#pragma unroll
    for (int c = 0; c < NCH; ++c) m = fmaxf(m, att[c]);
#pragma unroll
    for (int off = 32; off >= 1; off >>= 1) m = fmaxf(m, __shfl_down(m, off));
    const int wave = t >> 6;
    if ((t & 63) == 0) red[wave] = m;
    __syncthreads();
    m = fmaxf(fmaxf(red[0], red[1]), fmaxf(red[2], red[3]));

    float sum = 0.f;
#pragma unroll
    for (int c = 0; c < NCH; ++c) sum += __expf(att[c] - m);
#pragma unroll
    for (int off = 32; off >= 1; off >>= 1) sum += __shfl_down(sum, off);
    if ((t & 63) == 0) red[4 + wave] = sum;
    __syncthreads();
    sum = (red[4] + red[5]) + (red[6] + red[7]);

    const float logZ = m + __logf(sum);

    float* ob = out + (size_t)b * SS;
#pragma unroll
    for (int c = 0; c < NCH; ++c) ob[c * CHUNK + t] = att[c] - logZ;
}

extern "C" void kernel_launch(void* const* d_in, const int* in_sizes, int n_in,
                              void* d_out, int out_size, void* d_ws, size_t ws_size,
                              hipStream_t stream) {
    const float* dec = (const float*)d_in[0];  // decoder_hidden_final_layer [512,32]
    const float* enc = (const float*)d_in[1];  // encoder_outputs [512,4096,32]
    const float* Wq  = (const float*)d_in[2];  // [16,32]
    const float* bq  = (const float*)d_in[3];  // [16]
    const float* Wk  = (const float*)d_in[4];  // [16,32]
    const float* bk  = (const float*)d_in[5];  // [16]
    float* out = (float*)d_out;                // [512,1,4096]

    attn_cos_logsoftmax<<<dim3(BB), dim3(NT), 0, stream>>>(dec, enc, Wq, bq, Wk, bk, out);
}